// Round 17
// baseline (849.886 us; speedup 1.0000x reference)
//
#include <hip/hip_runtime.h>
#include <math.h>

#define N_PTS 131072
#define HID   256

typedef __attribute__((ext_vector_type(8)))  _Float16 f16x8;
typedef __attribute__((ext_vector_type(4)))  float    f32x4;
typedef __attribute__((ext_vector_type(16))) float    f32x16;

// act plane: rotate-swizzle within the 512B row -> b128 column reads conflict-free
__device__ __forceinline__ int act_addr(int row, int kbyte) {
    return row * 512 + ((kbyte + ((row & 31) << 4)) & 511);
}
// h = tanh(z), f1 = 1-h^2. Saturation-safe: s=inf -> h=1, f1=0.
__device__ __forceinline__ void tanh_f1(float z, float& h, float& f1) {
    float s = __expf(2.0f * z);
    float r = __builtin_amdgcn_rcpf(s + 1.0f);
    h  = fmaf(-2.0f, r, 1.0f);
    f1 = (1.0f - h) * (1.0f + h);
}

// Pre-cast W1..W3 to f16, packed per-wave/per-k-chunk (1KB units):
// unit = (l*16 + kc)*8 + wq;  wq = n>>5 (col-owner wave), kc = k>>4.
// byte = hh*512 + (n&31)*16 + (k&7)*2, hh=(k>>3)&1
// -> lane (hh,l31)'s 16B load at unit base + lane*16 IS its MFMA B-fragment.
// d_ws: 384 units x 1KB = 384KB (L2-resident).
__global__ void prep_w(const float* __restrict__ W1, const float* __restrict__ W2,
                       const float* __restrict__ W3, char* __restrict__ ws)
{
    int idx = blockIdx.x * 256 + threadIdx.x;     // 3*65536 elements
    int l = idx >> 16;
    int e = idx & 65535;
    int k = e >> 8, n = e & 255;
    const float* W = (l == 0) ? W1 : (l == 1) ? W2 : W3;
    float w = W[e];
    int kc = k >> 4, hh = (k >> 3) & 1, kl = k & 7;
    int wq = n >> 5, nn = n & 31;
    size_t base = (size_t)((l * 16 + kc) * 8 + wq) * 1024;
    int byte_in = hh * 512 + nn * 16 + kl * 2;
    *(_Float16*)(ws + base + byte_in) = (_Float16)w;
}

// Fused PINN forward + Taylor streams; 32x32x16 f16 MFMA, fp32 accum.
// GEMM row = S*p + s2 (point-interleaved), 64 rows/block. 8 waves; wave w owns
// cols [32w, 32w+32). B lives ENTIRELY IN VGPRs (bw[16] = 64 regs, loaded
// global->reg from L2; reload for layer l+1 issued right after each bw[ph]'s
// last use, covered by the rest of the K-loop + epilogue). K-loop is pure
// {2 ds_read_b128, 2 MFMA} — no LDS B-traffic, no staging, no vmcnt asm.
template<int S, int PTS>
__global__ void __launch_bounds__(512, 4)
pinn_mfma(const float* __restrict__ W0, const float* __restrict__ b0,
          const float* __restrict__ b1, const float* __restrict__ b2,
          const float* __restrict__ b3,
          const float* __restrict__ W4, const float* __restrict__ b4,
          const char* __restrict__ wpre,
          const float* __restrict__ tx, float* __restrict__ out)
{
    __shared__ char act[32768];        // act[64][512B], rotate-swizzled
    const int tid  = threadIdx.x;
    const int lane = tid & 63;
    const int wid  = tid >> 6;         // 0..7: cols [32*wid, 32*wid+32)
    const int l31  = lane & 31;
    const int hh   = lane >> 5;        // k-half select
    const int h16  = hh << 4;
    const int pbase = blockIdx.x * PTS;
    constexpr int CG = 512 / PTS;
    constexpr int NC = 256 / CG;
    const int ep  = tid / CG;
    const int ec0 = (tid % CG) * NC;

    // per-lane B source: unit (g*8 + wid), byte lane*16  (g = l*16 + ph)
    const char* srcW = wpre + (size_t)wid * 1024 + lane * 16;

    // B for layer 0 -> VGPRs (L2 latency hides under layer-0 elementwise)
    f16x8 bw[16];
    #pragma unroll
    for (int ph = 0; ph < 16; ++ph)
        bw[ph] = *(const f16x8*)(srcW + (size_t)ph * 8192);

    // ---------------- layer 0: 2 -> 256 (elementwise into LDS act) ----------------
    {
        const float tt = tx[2 * (pbase + ep) + 0];
        const float xx = tx[2 * (pbase + ep) + 1];
        for (int cb = ec0; cb < ec0 + NC; cb += 8) {
            alignas(16) float w0r[8], w1r[8], bb[8];
            *(f32x4*)&w0r[0] = *(const f32x4*)(W0 + cb);
            *(f32x4*)&w0r[4] = *(const f32x4*)(W0 + cb + 4);
            *(f32x4*)&w1r[0] = *(const f32x4*)(W0 + HID + cb);
            *(f32x4*)&w1r[4] = *(const f32x4*)(W0 + HID + cb + 4);
            *(f32x4*)&bb[0]  = *(const f32x4*)(b0 + cb);
            *(f32x4*)&bb[4]  = *(const f32x4*)(b0 + cb + 4);
            f16x8 vhi[S];
            #pragma unroll
            for (int j = 0; j < 8; ++j) {
                float z = fmaf(tt, w0r[j], fmaf(xx, w1r[j], bb[j]));
                float h, f1;
                tanh_f1(z, h, f1);
                vhi[0][j] = (_Float16)h;
                if (S == 2) {
                    vhi[1][j] = (_Float16)(f1 * w0r[j]);
                } else if (S == 4) {
                    float d1 = w0r[j] + w1r[j];
                    float d2 = w0r[j] - w1r[j];
                    float f2 = -2.0f * h * f1;
                    vhi[1][j] = (_Float16)(f1 * d1);
                    vhi[2][j] = (_Float16)(f1 * d2);
                    vhi[3][j] = (_Float16)(f2 * d1 * d2);
                }
            }
            #pragma unroll
            for (int s2 = 0; s2 < S; ++s2) {
                int row = ep * S + s2;      // point-interleaved
                *(f16x8*)(act + act_addr(row, cb * 2)) = vhi[s2];
            }
        }
    }

    // bias preload: 3 scalars (one column per lane)
    const int c0 = wid * 32 + l31;
    const float b1a = b1[c0];
    const float b2a = b2[c0];
    const float b3a = b3[c0];

    asm volatile("s_waitcnt lgkmcnt(0)" ::: "memory");   // act writes visible
    __builtin_amdgcn_sched_barrier(0);
    __builtin_amdgcn_s_barrier();
    __builtin_amdgcn_sched_barrier(0);

    // ---------------- layers 1..3: 256 -> 256 (runtime l-loop) ----------------
    for (int l = 0; l < 3; ++l) {
        const float bias = (l == 0) ? b1a : (l == 1) ? b2a : b3a;
        const char* srcNext = srcW + (size_t)(l + 1) * 131072;
        const bool reload = (l < 2);

        f32x16 acc0 = (f32x16){0.f,0.f,0.f,0.f,0.f,0.f,0.f,0.f,
                               0.f,0.f,0.f,0.f,0.f,0.f,0.f,0.f};
        f32x16 acc1 = acc0;

        #pragma unroll
        for (int ph = 0; ph < 16; ++ph) {       // BK=16 phases, pure LDS+MFMA
            const int kbyte = ph * 32 + h16;
            f16x8 av0 = *(const f16x8*)(act + act_addr(l31,      kbyte));
            f16x8 av1 = *(const f16x8*)(act + act_addr(32 + l31, kbyte));

            __builtin_amdgcn_s_setprio(1);
            acc0 = __builtin_amdgcn_mfma_f32_32x32x16_f16(av0, bw[ph], acc0, 0, 0, 0);
            acc1 = __builtin_amdgcn_mfma_f32_32x32x16_f16(av1, bw[ph], acc1, 0, 0, 0);
            __builtin_amdgcn_s_setprio(0);

            // bw[ph] is dead now -> reload it for the next layer; latency is
            // covered by the remaining phases + the whole epilogue.
            if (reload)
                bw[ph] = *(const f16x8*)(srcNext + (size_t)ph * 8192);
        }
        __builtin_amdgcn_s_barrier();   // all waves done READING act this layer

        // ---- in-register epilogue ----
        // C/D: col = wid*32 + l31; row-in-tile = (reg&3)+8*(reg>>2)+4*hh
        const bool lastL = (l == 2);
        const int colj = wid * 32 + l31;
        #pragma unroll
        for (int i = 0; i < 2; ++i) {
            const f32x16& A = i ? acc1 : acc0;
            const int rtb = i * 32 + 4 * hh;
            #pragma unroll
            for (int q = 0; q < 4; ++q) {
                const int rb = rtb + 8 * q;
                if (S == 4) {
                    float z0 = A[4*q+0] + bias;
                    float z1 = A[4*q+1];
                    float z2 = A[4*q+2];
                    float zm = A[4*q+3];
                    float h, f1;
                    tanh_f1(z0, h, f1);
                    float f2 = -2.0f * h * f1;
                    if (!lastL) {   // layer 4 reads only the mixed stream
                        *(_Float16*)(act + act_addr(rb+0, colj*2)) = (_Float16)h;
                        *(_Float16*)(act + act_addr(rb+1, colj*2)) = (_Float16)(f1 * z1);
                        *(_Float16*)(act + act_addr(rb+2, colj*2)) = (_Float16)(f1 * z2);
                    }
                    *(_Float16*)(act + act_addr(rb+3, colj*2)) =
                        (_Float16)(fmaf(f1, zm, f2 * z1 * z2));
                } else if (S == 2) {
                    #pragma unroll
                    for (int pp = 0; pp < 2; ++pp) {
                        float z0 = A[4*q+2*pp+0] + bias;
                        float zd = A[4*q+2*pp+1];
                        float h, f1;
                        tanh_f1(z0, h, f1);
                        *(_Float16*)(act + act_addr(rb+2*pp+0, colj*2)) = (_Float16)h;
                        *(_Float16*)(act + act_addr(rb+2*pp+1, colj*2)) = (_Float16)(f1 * zd);
                    }
                } else {
                    #pragma unroll
                    for (int m = 0; m < 4; ++m) {
                        float z0 = A[4*q+m] + bias;
                        float h, f1;
                        tanh_f1(z0, h, f1);
                        *(_Float16*)(act + act_addr(rb+m, colj*2)) = (_Float16)h;
                    }
                }
            }
        }
        asm volatile("s_waitcnt lgkmcnt(0)" ::: "memory");
        __builtin_amdgcn_sched_barrier(0);
        __builtin_amdgcn_s_barrier();   // new act visible
        __builtin_amdgcn_sched_barrier(0);
    }

    // ---------------- layer 4: 256 -> 1 ----------------
    if (S == 4) {
        // only the mixed stream (rows 4p+3) is needed
        const int p   = tid >> 5;     // 0..15
        const int seg = tid & 31;     // 32 lanes per point
        const int k0  = seg * 8;
        const int row = 4 * p + 3;
        f16x8 h8 = *(const f16x8*)(act + act_addr(row, k0 * 2));
        alignas(16) float wv[8];
        *(f32x4*)&wv[0] = *(const f32x4*)(W4 + k0);
        *(f32x4*)&wv[4] = *(const f32x4*)(W4 + k0 + 4);
        float d = 0.0f;
        #pragma unroll
        for (int j = 0; j < 8; ++j) d = fmaf((float)h8[j], wv[j], d);
        #pragma unroll
        for (int off = 16; off > 0; off >>= 1) d += __shfl_down(d, off, 32);
        if (seg == 0) out[0 * N_PTS + pbase + p] = d;              // u_tt - u_xx
    } else {
        const int row = tid >> 3;     // 0..63
        const int seg = tid & 7;      // 8 lanes per row
        const int k0  = seg * 32;
        float d = 0.0f;
        #pragma unroll
        for (int kb = 0; kb < 32; kb += 8) {
            f16x8 h8 = *(const f16x8*)(act + act_addr(row, (k0 + kb) * 2));
            alignas(16) float wv[8];
            *(f32x4*)&wv[0] = *(const f32x4*)(W4 + k0 + kb);
            *(f32x4*)&wv[4] = *(const f32x4*)(W4 + k0 + kb + 4);
            #pragma unroll
            for (int j = 0; j < 8; ++j) d = fmaf((float)h8[j], wv[j], d);
        }
        d += __shfl_down(d, 4, 8);
        d += __shfl_down(d, 2, 8);
        d += __shfl_down(d, 1, 8);
        if (seg == 0) {
            if (S == 2) {
                const int p = row >> 1;
                if ((row & 1) == 0) out[1 * N_PTS + pbase + p] = d + b4[0];   // u_phi
                else                out[2 * N_PTS + pbase + p] = d;           // du/dt
            } else {
                out[3 * N_PTS + pbase + row] = d + b4[0];                     // u_bound
            }
        }
    }
}

extern "C" void kernel_launch(void* const* d_in, const int* in_sizes, int n_in,
                              void* d_out, int out_size, void* d_ws, size_t ws_size,
                              hipStream_t stream) {
    const float* W0 = (const float*)d_in[0];
    const float* b0 = (const float*)d_in[1];
    const float* W1 = (const float*)d_in[2];
    const float* b1 = (const float*)d_in[3];
    const float* W2 = (const float*)d_in[4];
    const float* b2 = (const float*)d_in[5];
    const float* W3 = (const float*)d_in[6];
    const float* b3 = (const float*)d_in[7];
    const float* W4 = (const float*)d_in[8];
    const float* b4 = (const float*)d_in[9];
    const float* tx_eq    = (const float*)d_in[10];
    const float* tx_init  = (const float*)d_in[11];
    const float* tx_bound = (const float*)d_in[12];
    float* out = (float*)d_out;
    char* wpre = (char*)d_ws;     // needs 384KB

    prep_w<<<768, 256, 0, stream>>>(W1, W2, W3, wpre);
    pinn_mfma<4,16><<<N_PTS/16, 512, 0, stream>>>(W0,b0,b1,b2,b3,W4,b4,wpre,tx_eq,   out);
    pinn_mfma<2,32><<<N_PTS/32, 512, 0, stream>>>(W0,b0,b1,b2,b3,W4,b4,wpre,tx_init, out);
    pinn_mfma<1,64><<<N_PTS/64, 512, 0, stream>>>(W0,b0,b1,b2,b3,W4,b4,wpre,tx_bound,out);
}

// Round 18
// 673.228 us; speedup vs baseline: 1.2624x; 1.2624x over previous
//
#include <hip/hip_runtime.h>
#include <math.h>

#define N_PTS 131072
#define HID   256

typedef __attribute__((ext_vector_type(8)))  _Float16 f16x8;
typedef __attribute__((ext_vector_type(4)))  float    f32x4;
typedef __attribute__((ext_vector_type(16))) float    f32x16;

// act plane: rotate-swizzle within the 512B row -> b128 column reads conflict-free
__device__ __forceinline__ int act_addr(int row, int kbyte) {
    return row * 512 + ((kbyte + ((row & 31) << 4)) & 511);
}
// h = tanh(z), f1 = 1-h^2. Saturation-safe: s=inf -> h=1, f1=0.
__device__ __forceinline__ void tanh_f1(float z, float& h, float& f1) {
    float s = __expf(2.0f * z);
    float r = __builtin_amdgcn_rcpf(s + 1.0f);
    h  = fmaf(-2.0f, r, 1.0f);
    f1 = (1.0f - h) * (1.0f + h);
}

// Pre-cast W1..W3 to f16, packed per-wave/per-k-chunk (1KB units):
// unit = (l*16 + kc)*8 + wq;  wq = n>>5 (col-owner wave), kc = k>>4.
// byte = hh*512 + (n&31)*16 + (k&7)*2, hh=(k>>3)&1
// -> lane (hh,l31)'s 16B load at unit base + lane*16 IS its MFMA B-fragment.
// d_ws: 384 units x 1KB = 384KB (L2-resident).
__global__ void prep_w(const float* __restrict__ W1, const float* __restrict__ W2,
                       const float* __restrict__ W3, char* __restrict__ ws)
{
    int idx = blockIdx.x * 256 + threadIdx.x;     // 3*65536 elements
    int l = idx >> 16;
    int e = idx & 65535;
    int k = e >> 8, n = e & 255;
    const float* W = (l == 0) ? W1 : (l == 1) ? W2 : W3;
    float w = W[e];
    int kc = k >> 4, hh = (k >> 3) & 1, kl = k & 7;
    int wq = n >> 5, nn = n & 31;
    size_t base = (size_t)((l * 16 + kc) * 8 + wq) * 1024;
    int byte_in = hh * 512 + nn * 16 + kl * 2;
    *(_Float16*)(ws + base + byte_in) = (_Float16)w;
}

// Fused PINN forward + Taylor streams; 32x32x16 f16 MFMA, fp32 accum.
// GEMM row = S*p + s2 (point-interleaved), 64 rows/block. 8 waves; wave w owns
// cols [32w, 32w+32). B in a 4-SLOT VGPR RING (16 regs): slot ph&3 holds slab
// g = l*16+ph; after its MFMA use, the slot reloads slab g+4 (distance-4,
// ~4 phases of cover; compiler emits counted vmcnt automatically). 16%4==0
// keeps slot indices compile-time across the runtime l-loop -> no scratch.
// K-loop = {2 ds_read_b128, 2 MFMA, 1 global_load} — no staging, no asm.
template<int S, int PTS>
__global__ void __launch_bounds__(512, 4)
pinn_mfma(const float* __restrict__ W0, const float* __restrict__ b0,
          const float* __restrict__ b1, const float* __restrict__ b2,
          const float* __restrict__ b3,
          const float* __restrict__ W4, const float* __restrict__ b4,
          const char* __restrict__ wpre,
          const float* __restrict__ tx, float* __restrict__ out)
{
    __shared__ char act[32768];        // act[64][512B], rotate-swizzled
    const int tid  = threadIdx.x;
    const int lane = tid & 63;
    const int wid  = tid >> 6;         // 0..7: cols [32*wid, 32*wid+32)
    const int l31  = lane & 31;
    const int hh   = lane >> 5;        // k-half select
    const int h16  = hh << 4;
    const int pbase = blockIdx.x * PTS;
    constexpr int CG = 512 / PTS;
    constexpr int NC = 256 / CG;
    const int ep  = tid / CG;
    const int ec0 = (tid % CG) * NC;

    // per-lane B source: unit (g*8 + wid), byte lane*16  (g = l*16 + ph)
    const char* srcW = wpre + (size_t)wid * 1024 + lane * 16;

    // warm the 4-slot B ring with slabs 0..3 (covered by layer-0 compute)
    f16x8 bw0 = *(const f16x8*)(srcW);
    f16x8 bw1 = *(const f16x8*)(srcW + 1 * 8192);
    f16x8 bw2 = *(const f16x8*)(srcW + 2 * 8192);
    f16x8 bw3 = *(const f16x8*)(srcW + 3 * 8192);

    // ---------------- layer 0: 2 -> 256 (elementwise into LDS act) ----------------
    {
        const float tt = tx[2 * (pbase + ep) + 0];
        const float xx = tx[2 * (pbase + ep) + 1];
        for (int cb = ec0; cb < ec0 + NC; cb += 8) {
            alignas(16) float w0r[8], w1r[8], bb[8];
            *(f32x4*)&w0r[0] = *(const f32x4*)(W0 + cb);
            *(f32x4*)&w0r[4] = *(const f32x4*)(W0 + cb + 4);
            *(f32x4*)&w1r[0] = *(const f32x4*)(W0 + HID + cb);
            *(f32x4*)&w1r[4] = *(const f32x4*)(W0 + HID + cb + 4);
            *(f32x4*)&bb[0]  = *(const f32x4*)(b0 + cb);
            *(f32x4*)&bb[4]  = *(const f32x4*)(b0 + cb + 4);
            f16x8 vhi[S];
            #pragma unroll
            for (int j = 0; j < 8; ++j) {
                float z = fmaf(tt, w0r[j], fmaf(xx, w1r[j], bb[j]));
                float h, f1;
                tanh_f1(z, h, f1);
                vhi[0][j] = (_Float16)h;
                if (S == 2) {
                    vhi[1][j] = (_Float16)(f1 * w0r[j]);
                } else if (S == 4) {
                    float d1 = w0r[j] + w1r[j];
                    float d2 = w0r[j] - w1r[j];
                    float f2 = -2.0f * h * f1;
                    vhi[1][j] = (_Float16)(f1 * d1);
                    vhi[2][j] = (_Float16)(f1 * d2);
                    vhi[3][j] = (_Float16)(f2 * d1 * d2);
                }
            }
            #pragma unroll
            for (int s2 = 0; s2 < S; ++s2) {
                int row = ep * S + s2;      // point-interleaved
                *(f16x8*)(act + act_addr(row, cb * 2)) = vhi[s2];
            }
        }
    }

    // bias preload: 3 scalars (one column per lane)
    const int c0 = wid * 32 + l31;
    const float b1a = b1[c0];
    const float b2a = b2[c0];
    const float b3a = b3[c0];

    asm volatile("s_waitcnt lgkmcnt(0)" ::: "memory");   // act writes visible
    __builtin_amdgcn_sched_barrier(0);
    __builtin_amdgcn_s_barrier();
    __builtin_amdgcn_sched_barrier(0);

    // ---------------- layers 1..3: 256 -> 256 (runtime l-loop) ----------------
    for (int l = 0; l < 3; ++l) {
        const float bias = (l == 0) ? b1a : (l == 1) ? b2a : b3a;
        const char* srcL = srcW + (size_t)l * 131072;    // slab g at + ph*8192

        f32x16 acc0 = (f32x16){0.f,0.f,0.f,0.f,0.f,0.f,0.f,0.f,
                               0.f,0.f,0.f,0.f,0.f,0.f,0.f,0.f};
        f32x16 acc1 = acc0;

        #pragma unroll
        for (int ph = 0; ph < 16; ++ph) {       // BK=16 phases
            const int kbyte = ph * 32 + h16;
            f16x8 av0 = *(const f16x8*)(act + act_addr(l31,      kbyte));
            f16x8 av1 = *(const f16x8*)(act + act_addr(32 + l31, kbyte));
            f16x8 bv = (ph & 3) == 0 ? bw0 : (ph & 3) == 1 ? bw1
                     : (ph & 3) == 2 ? bw2 : bw3;

            __builtin_amdgcn_s_setprio(1);
            acc0 = __builtin_amdgcn_mfma_f32_32x32x16_f16(av0, bv, acc0, 0, 0, 0);
            acc1 = __builtin_amdgcn_mfma_f32_32x32x16_f16(av1, bv, acc1, 0, 0, 0);
            __builtin_amdgcn_s_setprio(0);

            // reload this slot with slab g+4 (distance-4; spans layer boundary)
            if (l < 2 || ph < 12) {
                const f16x8 nb = *(const f16x8*)(srcL + (size_t)(ph + 4) * 8192);
                if      ((ph & 3) == 0) bw0 = nb;
                else if ((ph & 3) == 1) bw1 = nb;
                else if ((ph & 3) == 2) bw2 = nb;
                else                    bw3 = nb;
            }
        }
        __builtin_amdgcn_s_barrier();   // all waves done READING act this layer

        // ---- in-register epilogue ----
        // C/D: col = wid*32 + l31; row-in-tile = (reg&3)+8*(reg>>2)+4*hh
        const bool lastL = (l == 2);
        const int colj = wid * 32 + l31;
        #pragma unroll
        for (int i = 0; i < 2; ++i) {
            const f32x16& A = i ? acc1 : acc0;
            const int rtb = i * 32 + 4 * hh;
            #pragma unroll
            for (int q = 0; q < 4; ++q) {
                const int rb = rtb + 8 * q;
                if (S == 4) {
                    float z0 = A[4*q+0] + bias;
                    float z1 = A[4*q+1];
                    float z2 = A[4*q+2];
                    float zm = A[4*q+3];
                    float h, f1;
                    tanh_f1(z0, h, f1);
                    float f2 = -2.0f * h * f1;
                    if (!lastL) {   // layer 4 reads only the mixed stream
                        *(_Float16*)(act + act_addr(rb+0, colj*2)) = (_Float16)h;
                        *(_Float16*)(act + act_addr(rb+1, colj*2)) = (_Float16)(f1 * z1);
                        *(_Float16*)(act + act_addr(rb+2, colj*2)) = (_Float16)(f1 * z2);
                    }
                    *(_Float16*)(act + act_addr(rb+3, colj*2)) =
                        (_Float16)(fmaf(f1, zm, f2 * z1 * z2));
                } else if (S == 2) {
                    #pragma unroll
                    for (int pp = 0; pp < 2; ++pp) {
                        float z0 = A[4*q+2*pp+0] + bias;
                        float zd = A[4*q+2*pp+1];
                        float h, f1;
                        tanh_f1(z0, h, f1);
                        *(_Float16*)(act + act_addr(rb+2*pp+0, colj*2)) = (_Float16)h;
                        *(_Float16*)(act + act_addr(rb+2*pp+1, colj*2)) = (_Float16)(f1 * zd);
                    }
                } else {
                    #pragma unroll
                    for (int m = 0; m < 4; ++m) {
                        float z0 = A[4*q+m] + bias;
                        float h, f1;
                        tanh_f1(z0, h, f1);
                        *(_Float16*)(act + act_addr(rb+m, colj*2)) = (_Float16)h;
                    }
                }
            }
        }
        asm volatile("s_waitcnt lgkmcnt(0)" ::: "memory");
        __builtin_amdgcn_sched_barrier(0);
        __builtin_amdgcn_s_barrier();   // new act visible
        __builtin_amdgcn_sched_barrier(0);
    }

    // ---------------- layer 4: 256 -> 1 ----------------
    if (S == 4) {
        // only the mixed stream (rows 4p+3) is needed
        const int p   = tid >> 5;     // 0..15
        const int seg = tid & 31;     // 32 lanes per point
        const int k0  = seg * 8;
        const int row = 4 * p + 3;
        f16x8 h8 = *(const f16x8*)(act + act_addr(row, k0 * 2));
        alignas(16) float wv[8];
        *(f32x4*)&wv[0] = *(const f32x4*)(W4 + k0);
        *(f32x4*)&wv[4] = *(const f32x4*)(W4 + k0 + 4);
        float d = 0.0f;
        #pragma unroll
        for (int j = 0; j < 8; ++j) d = fmaf((float)h8[j], wv[j], d);
        #pragma unroll
        for (int off = 16; off > 0; off >>= 1) d += __shfl_down(d, off, 32);
        if (seg == 0) out[0 * N_PTS + pbase + p] = d;              // u_tt - u_xx
    } else {
        const int row = tid >> 3;     // 0..63
        const int seg = tid & 7;      // 8 lanes per row
        const int k0  = seg * 32;
        float d = 0.0f;
        #pragma unroll
        for (int kb = 0; kb < 32; kb += 8) {
            f16x8 h8 = *(const f16x8*)(act + act_addr(row, (k0 + kb) * 2));
            alignas(16) float wv[8];
            *(f32x4*)&wv[0] = *(const f32x4*)(W4 + k0 + kb);
            *(f32x4*)&wv[4] = *(const f32x4*)(W4 + k0 + kb + 4);
            #pragma unroll
            for (int j = 0; j < 8; ++j) d = fmaf((float)h8[j], wv[j], d);
        }
        d += __shfl_down(d, 4, 8);
        d += __shfl_down(d, 2, 8);
        d += __shfl_down(d, 1, 8);
        if (seg == 0) {
            if (S == 2) {
                const int p = row >> 1;
                if ((row & 1) == 0) out[1 * N_PTS + pbase + p] = d + b4[0];   // u_phi
                else                out[2 * N_PTS + pbase + p] = d;           // du/dt
            } else {
                out[3 * N_PTS + pbase + row] = d + b4[0];                     // u_bound
            }
        }
    }
}

extern "C" void kernel_launch(void* const* d_in, const int* in_sizes, int n_in,
                              void* d_out, int out_size, void* d_ws, size_t ws_size,
                              hipStream_t stream) {
    const float* W0 = (const float*)d_in[0];
    const float* b0 = (const float*)d_in[1];
    const float* W1 = (const float*)d_in[2];
    const float* b1 = (const float*)d_in[3];
    const float* W2 = (const float*)d_in[4];
    const float* b2 = (const float*)d_in[5];
    const float* W3 = (const float*)d_in[6];
    const float* b3 = (const float*)d_in[7];
    const float* W4 = (const float*)d_in[8];
    const float* b4 = (const float*)d_in[9];
    const float* tx_eq    = (const float*)d_in[10];
    const float* tx_init  = (const float*)d_in[11];
    const float* tx_bound = (const float*)d_in[12];
    float* out = (float*)d_out;
    char* wpre = (char*)d_ws;     // needs 384KB

    prep_w<<<768, 256, 0, stream>>>(W1, W2, W3, wpre);
    pinn_mfma<4,16><<<N_PTS/16, 512, 0, stream>>>(W0,b0,b1,b2,b3,W4,b4,wpre,tx_eq,   out);
    pinn_mfma<2,32><<<N_PTS/32, 512, 0, stream>>>(W0,b0,b1,b2,b3,W4,b4,wpre,tx_init, out);
    pinn_mfma<1,64><<<N_PTS/64, 512, 0, stream>>>(W0,b0,b1,b2,b3,W4,b4,wpre,tx_bound,out);
}